// Round 6
// baseline (612.292 us; speedup 1.0000x reference)
//
#include <hip/hip_runtime.h>
#include <hip/hip_bf16.h>
#include <cstdint>
#include <cstddef>

#define N_NODES 200000
#define DIM 256
#define P_EDGES 65536
#define INV_TEMP 5.0f
#define NBLK_EDGE (P_EDGES / 16)     // 4096 blocks, 16 edges/block
#define NTILES (N_NODES / 64)        // 3125 row-tiles of 64 nodes
#define GEMM_BLOCKS 512              // persistent blocks, 2/CU

typedef __attribute__((ext_vector_type(8))) short short8;
typedef __attribute__((ext_vector_type(4))) float f32x4;

__device__ __forceinline__ unsigned short f2bf(float f) {
    unsigned int x = __float_as_uint(f);
    x = (x + 0x7FFFu + ((x >> 16) & 1u)) >> 16;   // RNE (inputs finite)
    return (unsigned short)x;
}
__device__ __forceinline__ float bf2f(unsigned short u) {
    return __uint_as_float(((unsigned int)u) << 16);
}

// async global -> LDS, 16B per lane. LDS dest = wave-uniform base + lane*16.
__device__ __forceinline__ void gload_lds16(const unsigned short* g, unsigned short* l) {
    __builtin_amdgcn_global_load_lds(
        (const __attribute__((address_space(1))) unsigned int*)(g),
        (__attribute__((address_space(3))) unsigned int*)(l),
        16, 0, 0);
}

// ---------------------------------------------------------------------------
// Kernel 1: convert emb (205MB f32) + W_src/W_dst -> bf16 in ws. Pure
// streaming float4->ushort4, grid-stride; saturates HBM.
// ---------------------------------------------------------------------------
__global__ __launch_bounds__(256) void convert_all(
    const float* __restrict__ emb, const float* __restrict__ Wsrc,
    const float* __restrict__ Wdst,
    unsigned short* __restrict__ embB, unsigned short* __restrict__ Wsb,
    unsigned short* __restrict__ Wdb)
{
    const long stride = (long)gridDim.x * 256;
    const long total_emb = (long)N_NODES * DIM / 4;      // 12.8M float4 granules
    for (long i = (long)blockIdx.x * 256 + threadIdx.x; i < total_emb; i += stride) {
        float4 v = ((const float4*)emb)[i];
        ushort4 h;
        h.x = f2bf(v.x); h.y = f2bf(v.y); h.z = f2bf(v.z); h.w = f2bf(v.w);
        ((ushort4*)embB)[i] = h;
    }
    for (long i = (long)blockIdx.x * 256 + threadIdx.x; i < 2 * DIM * DIM / 4; i += stride) {
        const float4* src = (i < DIM * DIM / 4) ? (const float4*)Wsrc : (const float4*)Wdst;
        unsigned short* dst = (i < DIM * DIM / 4) ? Wsb : Wdb;
        long off = i & (DIM * DIM / 4 - 1);
        float4 v = src[off];
        ushort4 h;
        h.x = f2bf(v.x); h.y = f2bf(v.y); h.z = f2bf(v.z); h.w = f2bf(v.w);
        *reinterpret_cast<ushort4*>(dst + off * 4) = h;
    }
}

// ---------------------------------------------------------------------------
// Kernel 2: Zs = l2norm_rows(embB @ Wsrc^T), Zd = l2norm_rows(embB @ Wdst^T).
// Persistent: 512 blocks x 256 thr (4 waves) grid-stride over 3125 tiles of
// 64 nodes. Tile (64x256 bf16 = 32KB) double-buffered in LDS via
// global_load_lds DMA: STAGE(t+1) issued BEFORE compute(t); the barrier
// drain lands after compute (m97 2-phase pattern).
// LDS swizzle (rule #21): linear DMA dest + inverse-swizzled global source;
// reads use chunk ^= (row&7) -> even 8-access/bank (b128 floor) ds_read_b128.
// Wave wv = mat*2+half owns a 128-feature band of one matrix: W read once
// per block-tile; MFMA operands swapped (A=W, B=emb) so D rows = features
// (contiguous ushort4 stores), D cols = nodes.
// ---------------------------------------------------------------------------
__global__ __launch_bounds__(256, 2) void proj_gemm(
    const unsigned short* __restrict__ embB,
    const unsigned short* __restrict__ Wsb,
    const unsigned short* __restrict__ Wdb,
    unsigned short* __restrict__ Zs,
    unsigned short* __restrict__ Zd)
{
    __shared__ unsigned short As[2][64 * 256];   // 2 x 32 KB, linear (DMA dest)
    __shared__ float partial[4][64];             // [wave][node] band sum-of-squares

    const int tid = threadIdx.x;
    const int lane = tid & 63;
    const int wv = tid >> 6;            // 0..3
    const int l15 = lane & 15;
    const int grp = lane >> 4;
    const int mat = wv >> 1;            // 0: src, 1: dst
    const int half = wv & 1;            // 128-feature half
    const int e3 = l15 & 7;             // read-swizzle key (row&7 == l15&7)

    const unsigned short* __restrict__ W = (mat ? Wdb : Wsb) + (size_t)(half * 128) * DIM;
    unsigned short* __restrict__ out = mat ? Zd : Zs;

    // stage tile t into buffer b: wave wv covers rows [wv*16, wv*16+16)
    // slot s = wv*512 + i*64 + lane (16B granules of the 64x256 u16 tile);
    // global source inverse-swizzled: chunk_mem = (s&31) ^ (row&7)
    auto STAGE = [&](int t, int b) {
        const unsigned short* gt = embB + (size_t)t * (64 * 256);
        #pragma unroll
        for (int i = 0; i < 8; ++i) {
            const int s = wv * 512 + i * 64 + lane;
            const int r = s >> 5;
            const int cd = (s & 31) ^ (r & 7);
            gload_lds16(gt + r * 256 + cd * 8, &As[b][(wv * 512 + i * 64) * 8]);
        }
    };

    int t = blockIdx.x;
    int cur = 0;
    STAGE(t, 0);
    __syncthreads();

    for (; t < NTILES; t += GEMM_BLOCKS) {
        const int tn = t + GEMM_BLOCKS;
        if (tn < NTILES) STAGE(tn, cur ^ 1);     // issue next-tile DMA first

        // ---- compute tile t from As[cur] (overlaps the DMA above) ----
        f32x4 acc[4][8];                          // [node-tile][feat-tile]
        #pragma unroll
        for (int nt = 0; nt < 4; ++nt)
            #pragma unroll
            for (int f = 0; f < 8; ++f) acc[nt][f] = (f32x4){0.f, 0.f, 0.f, 0.f};

        #pragma unroll
        for (int ks = 0; ks < 8; ++ks) {
            const int c = ((ks << 2) | grp) ^ e3;       // swizzled 16B chunk
            short8 ef[4];
            #pragma unroll
            for (int nt = 0; nt < 4; ++nt)
                ef[nt] = *reinterpret_cast<const short8*>(
                    &As[cur][(nt * 16 + l15) * 256 + c * 8]);
            #pragma unroll
            for (int f = 0; f < 8; ++f) {
                short8 wf = *reinterpret_cast<const short8*>(
                    W + (size_t)(f * 16 + l15) * DIM + ks * 32 + grp * 8);
                #pragma unroll
                for (int nt = 0; nt < 4; ++nt)
                    acc[nt][f] = __builtin_amdgcn_mfma_f32_16x16x32_bf16(
                        wf, ef[nt], acc[nt][f], 0, 0, 0);
            }
        }

        // ---- epilogue: cross-wave row norms, store bf16 ----
        #pragma unroll
        for (int nt = 0; nt < 4; ++nt) {
            float ssq = 0.f;
            #pragma unroll
            for (int f = 0; f < 8; ++f)
                #pragma unroll
                for (int r = 0; r < 4; ++r) { float x = acc[nt][f][r]; ssq += x * x; }
            ssq += __shfl_xor(ssq, 16);
            ssq += __shfl_xor(ssq, 32);
            if (grp == 0) partial[wv][nt * 16 + l15] = ssq;
        }
        __syncthreads();   // also drains next-tile DMA (after compute: overlap kept)

        const int row0 = t * 64;
        #pragma unroll
        for (int nt = 0; nt < 4; ++nt) {
            const int node = nt * 16 + l15;
            const float tot = partial[mat * 2 + 0][node] + partial[mat * 2 + 1][node];
            const float inv = rsqrtf(fmaxf(tot, 1e-24f));
            unsigned short* orow = out + (size_t)(row0 + node) * DIM + half * 128 + grp * 4;
            #pragma unroll
            for (int f = 0; f < 8; ++f) {
                ushort4 h;
                h.x = f2bf(acc[nt][f][0] * inv);
                h.y = f2bf(acc[nt][f][1] * inv);
                h.z = f2bf(acc[nt][f][2] * inv);
                h.w = f2bf(acc[nt][f][3] * inv);
                *reinterpret_cast<ushort4*>(orow + f * 16) = h;
            }
        }
        __syncthreads();   // guard partial[] + LDS buffer reuse
        cur ^= 1;
    }
}

// ---------------------------------------------------------------------------
// Kernel 3: per-edge loss, one edge per 16-lane group (16 edges/block).
// Per lane: 32 contiguous bytes of each row (2x b128), 4-step shfl reduce.
// Block partials -> ws (no atomics; deterministic).
// ---------------------------------------------------------------------------
__global__ __launch_bounds__(256) void edge_loss(
    const unsigned short* __restrict__ Zs,
    const unsigned short* __restrict__ Zd,
    const int* __restrict__ pos_src, const int* __restrict__ pos_dst,
    const int* __restrict__ pos_sign,
    const int* __restrict__ neg_src, const int* __restrict__ neg_dst,
    float* __restrict__ partials)
{
    const int tid = threadIdx.x;
    const int l15 = tid & 15;
    const int g = tid >> 4;
    const int p = blockIdx.x * 16 + g;

    int su[9], sv[9];
    su[0] = pos_src[p]; sv[0] = pos_dst[p];
    #pragma unroll
    for (int k = 0; k < 8; ++k) { su[k + 1] = neg_src[p * 8 + k]; sv[k + 1] = neg_dst[p * 8 + k]; }

    float sims[9];
    #pragma unroll
    for (int j = 0; j < 9; ++j) {
        const unsigned short* ur = Zs + (size_t)su[j] * DIM + l15 * 16;
        const unsigned short* vr = Zd + (size_t)sv[j] * DIM + l15 * 16;
        short8 u0 = *reinterpret_cast<const short8*>(ur);
        short8 u1 = *reinterpret_cast<const short8*>(ur + 8);
        short8 v0 = *reinterpret_cast<const short8*>(vr);
        short8 v1 = *reinterpret_cast<const short8*>(vr + 8);
        float s = 0.f;
        #pragma unroll
        for (int i = 0; i < 8; ++i) {
            s += bf2f((unsigned short)u0[i]) * bf2f((unsigned short)v0[i]);
            s += bf2f((unsigned short)u1[i]) * bf2f((unsigned short)v1[i]);
        }
        s += __shfl_xor(s, 1);
        s += __shfl_xor(s, 2);
        s += __shfl_xor(s, 4);
        s += __shfl_xor(s, 8);
        sims[j] = s;
    }

    const int sg = pos_sign[p];
    float ln[9];
    ln[0] = (sg == 0 ? -sims[0] : sims[0]) * INV_TEMP;
    float m = ln[0];
    #pragma unroll
    for (int j = 1; j < 9; ++j) { ln[j] = sims[j] * INV_TEMP; m = fmaxf(m, ln[j]); }
    float se = 0.f;
    #pragma unroll
    for (int j = 0; j < 9; ++j) se += __expf(ln[j] - m);
    const float loss = m + __logf(se) - ln[0];
    const float use = (sg != 2) ? 1.f : 0.f;

    __shared__ float wl[16], wc[16];
    if (l15 == 0) { wl[g] = loss * use; wc[g] = use; }
    __syncthreads();
    if (tid == 0) {
        float L = 0.f, C = 0.f;
        #pragma unroll
        for (int i = 0; i < 16; ++i) { L += wl[i]; C += wc[i]; }
        partials[blockIdx.x * 2 + 0] = L;
        partials[blockIdx.x * 2 + 1] = C;
    }
}

// ---------------------------------------------------------------------------
__global__ __launch_bounds__(256) void finalize(const float* __restrict__ partials,
                                                float* __restrict__ out) {
    const int tid = threadIdx.x;
    float L = 0.f, C = 0.f;
    for (int i = tid; i < NBLK_EDGE; i += 256) {
        L += partials[i * 2 + 0];
        C += partials[i * 2 + 1];
    }
    #pragma unroll
    for (int s = 32; s >= 1; s >>= 1) {
        L += __shfl_xor(L, s);
        C += __shfl_xor(C, s);
    }
    __shared__ float sl[4], sc[4];
    if ((tid & 63) == 0) { sl[tid >> 6] = L; sc[tid >> 6] = C; }
    __syncthreads();
    if (tid == 0) {
        out[0] = (sl[0] + sl[1] + sl[2] + sl[3]) /
                 (sc[0] + sc[1] + sc[2] + sc[3] + 1e-9f);
    }
}

// ---------------------------------------------------------------------------
extern "C" void kernel_launch(void* const* d_in, const int* in_sizes, int n_in,
                              void* d_out, int out_size, void* d_ws, size_t ws_size,
                              hipStream_t stream) {
    const float* node_emb = (const float*)d_in[0];
    const float* W_src    = (const float*)d_in[1];
    const float* W_dst    = (const float*)d_in[2];
    const int* pos_src    = (const int*)d_in[3];
    const int* pos_dst    = (const int*)d_in[4];
    const int* pos_sign   = (const int*)d_in[5];
    const int* neg_src    = (const int*)d_in[6];
    const int* neg_dst    = (const int*)d_in[7];
    float* out = (float*)d_out;

    char* ws = (char*)d_ws;
    const size_t zbytes = (size_t)N_NODES * DIM * 2;           // 102,400,000 B
    unsigned short* embB = (unsigned short*)ws;
    unsigned short* Zs   = (unsigned short*)(ws + zbytes);
    unsigned short* Zd   = (unsigned short*)(ws + 2 * zbytes);
    unsigned short* Wsb  = (unsigned short*)(ws + 3 * zbytes);
    unsigned short* Wdb  = Wsb + DIM * DIM;
    float* partials = (float*)(Wdb + DIM * DIM);               // 32 KB

    hipLaunchKernelGGL(convert_all, dim3(2048), dim3(256), 0, stream,
                       node_emb, W_src, W_dst, embB, Wsb, Wdb);
    hipLaunchKernelGGL(proj_gemm, dim3(GEMM_BLOCKS), dim3(256), 0, stream,
                       embB, Wsb, Wdb, Zs, Zd);
    hipLaunchKernelGGL(edge_loss, dim3(NBLK_EDGE), dim3(256), 0, stream,
                       Zs, Zd, pos_src, pos_dst, pos_sign, neg_src, neg_dst, partials);
    hipLaunchKernelGGL(finalize, dim3(1), dim3(256), 0, stream, partials, out);
}